// Round 1
// 238.992 us; speedup vs baseline: 1.0470x; 1.0470x over previous
//
#include <hip/hip_runtime.h>
#include <hip/hip_bf16.h>
#include <cstdint>

typedef __bf16 bf16;
typedef __bf16 bf16x2 __attribute__((ext_vector_type(2)));
typedef __bf16 bf16x4 __attribute__((ext_vector_type(4)));
typedef __bf16 bf16x8 __attribute__((ext_vector_type(8)));
typedef float f32x4 __attribute__((ext_vector_type(4)));
typedef float f32x16 __attribute__((ext_vector_type(16)));
typedef unsigned int u32;

#define B_ 2
#define S_ 2048
#define DM 1024
#define H_ 16
#define HD 64

// async global->LDS 16B: lane l's 16 bytes land at ldsbase + l*16.
__device__ __forceinline__ void gload_lds16(const bf16* g, bf16* l) {
  __builtin_amdgcn_global_load_lds((const __attribute__((address_space(1))) void*)g,
                                   (__attribute__((address_space(3))) void*)l,
                                   16, 0, 0);
}

__device__ __forceinline__ u32 cvt_pk_bf16(float lo, float hi) {
  u32 r;
  asm("v_cvt_pk_bf16_f32 %0, %1, %2" : "=v"(r) : "v"(lo), "v"(hi));
  return r;
}

// ---------------------------------------------------------------------------
// fp32 -> bf16 elementwise convert for q/k/v activations. 8 elems/thread.
__global__ __launch_bounds__(256) void convert_k(const float* __restrict__ s0,
                                                 const float* __restrict__ s1,
                                                 const float* __restrict__ s2,
                                                 bf16* __restrict__ d0,
                                                 bf16* __restrict__ d1,
                                                 bf16* __restrict__ d2) {
  const float* s = (blockIdx.z == 0) ? s0 : (blockIdx.z == 1) ? s1 : s2;
  bf16* d = (blockIdx.z == 0) ? d0 : (blockIdx.z == 1) ? d1 : d2;
  const size_t i = ((size_t)blockIdx.x * 256 + threadIdx.x) * 8;
  f32x4 a = *(const f32x4*)(s + i);
  f32x4 b = *(const f32x4*)(s + i + 4);
  bf16x8 o;
#pragma unroll
  for (int j = 0; j < 4; j++) { o[j] = (bf16)a[j]; o[j + 4] = (bf16)b[j]; }
  *(bf16x8*)(d + i) = o;
}

// ---------------------------------------------------------------------------
// Transpose 4 fp32 1024x1024 weights -> bf16 W^T[n][k] in ws.
__global__ __launch_bounds__(256) void transposeW_k(
    const float* __restrict__ w0, const float* __restrict__ w1,
    const float* __restrict__ w2, const float* __restrict__ w3,
    bf16* __restrict__ t0, bf16* __restrict__ t1,
    bf16* __restrict__ t2, bf16* __restrict__ t3) {
  const float* src = (blockIdx.z == 0) ? w0 : (blockIdx.z == 1) ? w1
                     : (blockIdx.z == 2) ? w2 : w3;
  bf16* dst = (blockIdx.z == 0) ? t0 : (blockIdx.z == 1) ? t1
              : (blockIdx.z == 2) ? t2 : t3;
  __shared__ float tile[32][33];
  const int tx = threadIdx.x, ty = threadIdx.y;  // 32 x 8
  const int x0 = blockIdx.x * 32, y0 = blockIdx.y * 32;
#pragma unroll
  for (int r = 0; r < 4; r++)
    tile[ty + r * 8][tx] = src[(size_t)(y0 + ty + r * 8) * DM + x0 + tx];
  __syncthreads();
#pragma unroll
  for (int r = 0; r < 4; r++)
    dst[(size_t)(x0 + ty + r * 8) * DM + y0 + tx] = (bf16)tile[tx][ty + r * 8];
}

// ---------------------------------------------------------------------------
// C[M,N] = A[M,K] @ Bt[N,K]^T + bias. 128x128 tile, BK=32, 4 waves x (4x4)
// 16x16x32 bf16 MFMA. bf16 A: global_load_lds width-16 staging (m97).
struct GArgs { const void* A; const bf16* Bt; const float* bias; void* C; };
struct GArgs3 { GArgs g[3]; };

template <bool AF32, bool CF32>
__global__ __launch_bounds__(256) void gemm_k(GArgs3 args, int M, int N, int K) {
  const GArgs ga = args.g[blockIdx.z];
  __shared__ __align__(16) bf16 As[128 * 32];  // [m][k], stride 32
  __shared__ __align__(16) bf16 Bs[128 * 32];  // [n][k], stride 32
  const int tid = threadIdx.x;
  const int lane = tid & 63, w = tid >> 6;
  const int l15 = lane & 15, q = lane >> 4;
  const int wr = w >> 1, wc = w & 1;
  const int m0 = blockIdx.y * 128, n0 = blockIdx.x * 128;

  const int c0 = w * 128 + lane;       // wave-contiguous for global_load_lds
  const int c1 = c0 + 64;
  const int r0 = c0 >> 2, r1 = c1 >> 2, koff = (c0 & 3) * 8;
  const bf16* gB0 = ga.Bt + (size_t)(n0 + r0) * K + koff;
  const bf16* gB1 = ga.Bt + (size_t)(n0 + r1) * K + koff;
  bf16* lA0 = As + (w * 2 + 0) * 512;  // 64 lanes x 16B = 512 elems
  bf16* lA1 = As + (w * 2 + 1) * 512;
  bf16* lB0 = Bs + (w * 2 + 0) * 512;
  bf16* lB1 = Bs + (w * 2 + 1) * 512;

  const float* pA0 = nullptr;
  const float* pA1 = nullptr;
  f32x4 t00, t01, t10, t11;
  if constexpr (AF32) {
    const float* A = (const float*)ga.A;
    pA0 = A + (size_t)(m0 + r0) * K + koff;
    pA1 = A + (size_t)(m0 + r1) * K + koff;
    t00 = *(const f32x4*)pA0; t01 = *(const f32x4*)(pA0 + 4);
    t10 = *(const f32x4*)pA1; t11 = *(const f32x4*)(pA1 + 4);
  }

  f32x4 acc[4][4] = {};

  for (int k0 = 0; k0 < K; k0 += 32) {
    if constexpr (AF32) {
      bf16x8 va0, va1;
#pragma unroll
      for (int j = 0; j < 4; j++) {
        va0[j] = (bf16)t00[j]; va0[j + 4] = (bf16)t01[j];
        va1[j] = (bf16)t10[j]; va1[j + 4] = (bf16)t11[j];
      }
      *(bf16x8*)(lA0 + lane * 8) = va0;
      *(bf16x8*)(lA1 + lane * 8) = va1;
    } else {
      const bf16* A = (const bf16*)ga.A;
      gload_lds16(A + (size_t)(m0 + r0) * K + koff + k0, lA0);
      gload_lds16(A + (size_t)(m0 + r1) * K + koff + k0, lA1);
    }
    gload_lds16(gB0 + k0, lB0);
    gload_lds16(gB1 + k0, lB1);
    __syncthreads();  // drains async copies + LDS writes

    bf16x8 a[4], b[4];
#pragma unroll
    for (int mt = 0; mt < 4; mt++)
      a[mt] = *(const bf16x8*)(As + (wr * 64 + mt * 16 + l15) * 32 + q * 8);
#pragma unroll
    for (int nt = 0; nt < 4; nt++)
      b[nt] = *(const bf16x8*)(Bs + (wc * 64 + nt * 16 + l15) * 32 + q * 8);

    if constexpr (AF32) {  // prefetch next A chunk; overlaps MFMA below
      const int kn = (k0 + 32 < K) ? k0 + 32 : k0;
      t00 = *(const f32x4*)(pA0 + kn); t01 = *(const f32x4*)(pA0 + kn + 4);
      t10 = *(const f32x4*)(pA1 + kn); t11 = *(const f32x4*)(pA1 + kn + 4);
    }

#pragma unroll
    for (int mt = 0; mt < 4; mt++)
#pragma unroll
      for (int nt = 0; nt < 4; nt++)
        acc[mt][nt] = __builtin_amdgcn_mfma_f32_16x16x32_bf16(a[mt], b[nt],
                                                              acc[mt][nt], 0, 0, 0);
    __syncthreads();
  }

  // C/D layout: col = lane&15, row = (lane>>4)*4 + reg.
#pragma unroll
  for (int nt = 0; nt < 4; nt++) {
    const int col = n0 + wc * 64 + nt * 16 + l15;
    const float bv = ga.bias[col];
#pragma unroll
    for (int mt = 0; mt < 4; mt++) {
      const int row = m0 + wr * 64 + mt * 16 + q * 4;
#pragma unroll
      for (int r = 0; r < 4; r++) {
        const float val = acc[mt][nt][r] + bv;
        if constexpr (CF32)
          ((float*)ga.C)[(size_t)(row + r) * N + col] = val;
        else
          ((bf16*)ga.C)[(size_t)(row + r) * N + col] = (bf16)val;
      }
    }
  }
}

// ---------------------------------------------------------------------------
// Causal flash attention, no-max softmax. 32x32x16 MFMA, swapped QK^T
// (S^T = K@Q^T) so P stays in registers (cvt_pk_bf16 + permlane32_swap).
// 4 waves = (q-half qh) x (key-half kh). Each wave accumulates a partial
// O^T[64d][32q] over its key-half; one LDS reduction at block end.
// One block per 64-row Q tile; grid slot mapping gives each CU tiles
// {a,31-a,b,31-b} -> 66 iters per CU (perfect static balance), 4 blocks/CU.
__global__ __launch_bounds__(256, 4) void attn_k(const bf16* __restrict__ Qp,
                                                 const bf16* __restrict__ Kp,
                                                 const bf16* __restrict__ Vp,
                                                 bf16* __restrict__ Op) {
  const int g = blockIdx.x;          // 0..1023
  const int c = g & 255, sl = g >> 8;
  const int u = c & 31;
  const int xt = (sl == 0) ? u : (sl == 1) ? 31 - u
                 : (sl == 2) ? (u ^ 16) : 31 - (u ^ 16);
  const int h = (c >> 5) | ((sl & 1) << 3);
  const int b = sl >> 1;
  const int i0 = xt * 64;

  const int tid = threadIdx.x;
  const int lane = tid & 63, w = tid >> 6;
  const int l31 = lane & 31, hi = lane >> 5;
  const int qh = w >> 1, kh = w & 1;

  // 36864B: staging Ks/Vts; reused after the loop as f32 O^T partials (32KB)
  // + rsum partials (512B).
  __shared__ __align__(16) char smem[36864];
  bf16 (*Ks)[64][72] = (bf16 (*)[64][72])smem;             // [2][64][72]
  bf16 (*Vts)[64][72] = (bf16 (*)[64][72])(smem + 18432);  // [2][64][72] ([d][k])

  const size_t headoff = (size_t)b * S_ * DM + h * HD;
  const bf16* Kb = Kp + headoff;
  const bf16* Vb = Vp + headoff;

  const int kr0 = tid >> 3, kr1 = 32 + (tid >> 3), kcb = (tid & 7) * 8;
  const int d0 = (tid & 31) * 2, kq = (tid >> 5) * 8;
  const float QSCALE = 0.04508422f;  // log2(e)/32

  // ---- Q -> registers in B-frag layout (n=q=l31, k=kk*16+hi*8+j), prescaled
  bf16x8 qreg[4];
  {
    const bf16* qb = Qp + headoff + (size_t)(i0 + qh * 32 + l31) * DM + hi * 8;
#pragma unroll
    for (int kk = 0; kk < 4; kk++) {
      bf16x8 v = *(const bf16x8*)(qb + kk * 16);
      bf16x8 o;
#pragma unroll
      for (int j = 0; j < 8; j++) o[j] = (bf16)((float)v[j] * QSCALE);
      qreg[kk] = o;
    }
  }

  // ---- stage K/V tile j0=0 into buf 0
  {
    bf16x8 k0v = *(const bf16x8*)(Kb + (size_t)kr0 * DM + kcb);
    bf16x8 k1v = *(const bf16x8*)(Kb + (size_t)kr1 * DM + kcb);
    *(bf16x8*)&Ks[0][kr0][kcb] = k0v;
    *(bf16x8*)&Ks[0][kr1][kcb] = k1v;
    bf16x8 vlo, vhi;
#pragma unroll
    for (int j = 0; j < 8; j++) {
      bf16x2 p = *(const bf16x2*)(Vb + (size_t)(kq + j) * DM + d0);
      vlo[j] = p[0]; vhi[j] = p[1];
    }
    *(bf16x8*)&Vts[0][d0][kq] = vlo;
    *(bf16x8*)&Vts[0][d0 + 1][kq] = vhi;
  }
  __syncthreads();

  f32x16 oacc0 = {}, oacc1 = {};  // O^T partial: d-tiles 0..31 / 32..63, col q
  float rsum = 0.f;
  int buf = 0;

  for (int j0 = 0; j0 <= i0; j0 += 64, buf ^= 1) {
    // ---- prefetch next K/V tile into regs (T14: issue early, write late)
    const int jn = (j0 + 64 <= i0) ? j0 + 64 : 0;
    bf16x8 kpre0 = *(const bf16x8*)(Kb + (size_t)(jn + kr0) * DM + kcb);
    bf16x8 kpre1 = *(const bf16x8*)(Kb + (size_t)(jn + kr1) * DM + kcb);
    bf16x2 vpre[8];
#pragma unroll
    for (int j = 0; j < 8; j++)
      vpre[j] = *(const bf16x2*)(Vb + (size_t)(jn + kq + j) * DM + d0);

    const bool diag = (j0 == i0);
    if (!(diag && kh > qh)) {  // (qh=0,kh=1) diagonal tile is fully masked
      // ---- S^T = K @ Q^T : A = K[key=kh*32+l31][hd], B = Q regs
      f32x16 sacc = {};
      __builtin_amdgcn_s_setprio(1);
#pragma unroll
      for (int kk = 0; kk < 4; kk++) {
        bf16x8 ka = *(const bf16x8*)&Ks[buf][kh * 32 + l31][kk * 16 + hi * 8];
        sacc = __builtin_amdgcn_mfma_f32_32x32x16_bf16(ka, qreg[kk], sacc, 0, 0, 0);
      }
      __builtin_amdgcn_s_setprio(0);

      // ---- p = exp2(s). C-layout: col=q=l31, row=key=(r&3)+8*(r>>2)+4*hi
      float p[16];
      if (diag) {
        const int qrl = qh * 32 + l31;
#pragma unroll
        for (int r = 0; r < 16; r++) {
          const int keyl = kh * 32 + (r & 3) + 8 * (r >> 2) + 4 * hi;
          p[r] = (keyl <= qrl) ? __builtin_amdgcn_exp2f(sacc[r]) : 0.f;
          rsum += p[r];
        }
      } else {
#pragma unroll
        for (int r = 0; r < 16; r++) {
          p[r] = __builtin_amdgcn_exp2f(sacc[r]);
          rsum += p[r];
        }
      }

      // ---- pack quads (regs 4t..4t+3 hold keys 8t..8t+3 +4hi) to bf16 words
      u32 Aq[4][2];
#pragma unroll
      for (int t = 0; t < 4; t++) {
        Aq[t][0] = cvt_pk_bf16(p[4 * t + 0], p[4 * t + 1]);
        Aq[t][1] = cvt_pk_bf16(p[4 * t + 2], p[4 * t + 3]);
      }
      // ---- exchange to PV B-frag: lane (q,hi) step s needs keys 16s+8hi+j.
      // j0..3 from hi'=0 quad (2s+hi), j4..7 from hi'=1 quad (2s+hi):
      // permlane32_swap(A[2s],A[2s+1]) -> {[lo:own A2s | hi:partner A2s+1],
      //                                    [lo:partner A2s | hi:own A2s+1]}
      bf16x8 pb[2];
#pragma unroll
      for (int s = 0; s < 2; s++) {
        auto e0 = __builtin_amdgcn_permlane32_swap(Aq[2 * s][0], Aq[2 * s + 1][0], false, false);
        auto e1 = __builtin_amdgcn_permlane32_swap(Aq[2 * s][1], Aq[2 * s + 1][1], false, false);
        union { u32 u[4]; bf16x8 v; } cv;
        cv.u[0] = e0[0]; cv.u[1] = e1[0]; cv.u[2] = e0[1]; cv.u[3] = e1[1];
        pb[s] = cv.v;
      }

      // ---- O^T += V^T @ P : A = Vts[d][key], B = pb (keys of this kh-half)
      __builtin_amdgcn_s_setprio(1);
#pragma unroll
      for (int s = 0; s < 2; s++) {
        bf16x8 va0 = *(const bf16x8*)&Vts[buf][l31][kh * 32 + s * 16 + hi * 8];
        bf16x8 va1 = *(const bf16x8*)&Vts[buf][32 + l31][kh * 32 + s * 16 + hi * 8];
        oacc0 = __builtin_amdgcn_mfma_f32_32x32x16_bf16(va0, pb[s], oacc0, 0, 0, 0);
        oacc1 = __builtin_amdgcn_mfma_f32_32x32x16_bf16(va1, pb[s], oacc1, 0, 0, 0);
      }
      __builtin_amdgcn_s_setprio(0);
    }

    // ---- write prefetched tile into the other buffer
    *(bf16x8*)&Ks[buf ^ 1][kr0][kcb] = kpre0;
    *(bf16x8*)&Ks[buf ^ 1][kr1][kcb] = kpre1;
    {
      bf16x8 vlo, vhi;
#pragma unroll
      for (int j = 0; j < 8; j++) { vlo[j] = vpre[j][0]; vhi[j] = vpre[j][1]; }
      *(bf16x8*)&Vts[buf ^ 1][d0][kq] = vlo;
      *(bf16x8*)&Vts[buf ^ 1][d0 + 1][kq] = vhi;
    }
    __syncthreads();  // single barrier: buf^1 writes visible, buf reads done
  }

  // ---- cross-wave (kh) reduction + transposed coalesced output ----
  // intra-wave rsum: lanes (q,0)/(q,1) hold complementary key partial sums
  float rtot_w = rsum + __shfl_xor(rsum, 32);
  float* osum = (float*)smem;             // [w][slot=8][lane=64][4] f32
  float* auxf = (float*)(smem + 32768);   // [w][32] rsum partials
#pragma unroll
  for (int m = 0; m < 2; m++) {
#pragma unroll
    for (int rq = 0; rq < 4; rq++) {
      f32x4 v4;
#pragma unroll
      for (int e = 0; e < 4; e++)
        v4[e] = m ? oacc1[rq * 4 + e] : oacc0[rq * 4 + e];
      *(f32x4*)(osum + w * 2048 + (m * 4 + rq) * 256 + lane * 4) = v4;
    }
  }
  if (lane < 32) auxf[w * 32 + lane] = rtot_w;
  __syncthreads();

  // thread t: row q = t>>2 (0..63), cols (t&3)*16..+15.
  // element (q,d) lives at wave (qh2,kh): slot=(d>>5)*4+((d>>3)&3),
  // lane=(q&31)+32*((d>>2)&1), word=(d&3).
  {
    const int q = tid >> 2, q31b = q & 31, qh2 = q >> 5;
    const float rtot = auxf[(qh2 * 2 + 0) * 32 + q31b] + auxf[(qh2 * 2 + 1) * 32 + q31b];
    const float rinv = 1.0f / rtot;
    const int dbase = (tid & 3) * 16;
    bf16* orow = Op + headoff + (size_t)(i0 + q) * DM + dbase;
#pragma unroll
    for (int gg = 0; gg < 2; gg++) {
      bf16x8 o8;
#pragma unroll
      for (int e = 0; e < 8; e++) {
        const int d = dbase + gg * 8 + e;
        const int base = (((d >> 5) << 2) | ((d >> 3) & 3)) * 256 +
                         (q31b + 32 * ((d >> 2) & 1)) * 4 + (d & 3);
        const float v = osum[(qh2 * 2 + 0) * 2048 + base] +
                        osum[(qh2 * 2 + 1) * 2048 + base];
        o8[e] = (bf16)(v * rinv);
      }
      *(bf16x8*)(orow + gg * 8) = o8;
    }
  }
}

// ---------------------------------------------------------------------------
extern "C" void kernel_launch(void* const* d_in, const int* in_sizes, int n_in,
                              void* d_out, int out_size, void* d_ws, size_t ws_size,
                              hipStream_t stream) {
  const float* q_in = (const float*)d_in[0];
  const float* k_in = (const float*)d_in[1];
  const float* v_in = (const float*)d_in[2];
  // d_in[3] = causal mask, implemented analytically
  const float* Wq = (const float*)d_in[4];
  const float* bq = (const float*)d_in[5];
  const float* Wk = (const float*)d_in[6];
  const float* bk = (const float*)d_in[7];
  const float* Wv = (const float*)d_in[8];
  const float* bv = (const float*)d_in[9];
  const float* Wo = (const float*)d_in[10];
  const float* bo = (const float*)d_in[11];

  bf16* ws = (bf16*)d_ws;
  const size_t NQ = (size_t)B_ * S_ * DM;  // 4M elements
  bf16* Qp = ws;                           // attn writes in-place
  bf16* Kp = ws + NQ;
  bf16* Vp = ws + 2 * NQ;
  bf16* WqT = ws + 3 * NQ;                 // bf16 W^T, 1M elems each
  bf16* WkT = WqT + (size_t)DM * DM;
  bf16* WvT = WkT + (size_t)DM * DM;
  bf16* WoT = WvT + (size_t)DM * DM;       // 32 MB so far
  bf16* qb = WoT + (size_t)DM * DM;        // converted activations (fast path)
  bf16* kb = qb + NQ;
  bf16* vb = kb + NQ;                      // 56 MB total (fast path)

  const bool fast = ws_size >= (size_t)(28 * 1024 * 1024) * 2;  // 56 MB

  transposeW_k<<<dim3(32, 32, 4), dim3(32, 8), 0, stream>>>(
      Wq, Wk, Wv, Wo, WqT, WkT, WvT, WoT);

  if (fast) {
    convert_k<<<dim3((B_ * S_ * DM) / (256 * 8), 1, 3), 256, 0, stream>>>(
        q_in, k_in, v_in, qb, kb, vb);
    GArgs3 g3;
    g3.g[0] = {qb, WqT, bq, Qp};
    g3.g[1] = {kb, WkT, bk, Kp};
    g3.g[2] = {vb, WvT, bv, Vp};
    gemm_k<false, false><<<dim3(DM / 128, (B_ * S_) / 128, 3), 256, 0, stream>>>(
        g3, B_ * S_, DM, DM);
  } else {
    GArgs3 g3;
    g3.g[0] = {q_in, WqT, bq, Qp};
    g3.g[1] = {k_in, WkT, bk, Kp};
    g3.g[2] = {v_in, WvT, bv, Vp};
    gemm_k<true, false><<<dim3(DM / 128, (B_ * S_) / 128, 3), 256, 0, stream>>>(
        g3, B_ * S_, DM, DM);
  }

  attn_k<<<dim3(1024, 1, 1), 256, 0, stream>>>(Qp, Kp, Vp, Qp);

  GArgs3 gp;
  gp.g[0] = {Qp, WoT, bo, d_out};
  gp.g[1] = gp.g[0];
  gp.g[2] = gp.g[0];
  gemm_k<false, true><<<dim3(DM / 128, (B_ * S_) / 128, 1), 256, 0, stream>>>(
      gp, B_ * S_, DM, DM);
}

// Round 2
// 225.467 us; speedup vs baseline: 1.1098x; 1.0600x over previous
//
#include <hip/hip_runtime.h>
#include <hip/hip_bf16.h>
#include <cstdint>

typedef __bf16 bf16;
typedef __bf16 bf16x2 __attribute__((ext_vector_type(2)));
typedef __bf16 bf16x4 __attribute__((ext_vector_type(4)));
typedef __bf16 bf16x8 __attribute__((ext_vector_type(8)));
typedef float f32x4 __attribute__((ext_vector_type(4)));
typedef float f32x16 __attribute__((ext_vector_type(16)));
typedef unsigned int u32;

#define B_ 2
#define S_ 2048
#define DM 1024
#define H_ 16
#define HD 64

// async global->LDS 16B: lane l's 16 bytes land at ldsbase + l*16.
__device__ __forceinline__ void gload_lds16(const bf16* g, bf16* l) {
  __builtin_amdgcn_global_load_lds((const __attribute__((address_space(1))) void*)g,
                                   (__attribute__((address_space(3))) void*)l,
                                   16, 0, 0);
}

__device__ __forceinline__ u32 cvt_pk_bf16(float lo, float hi) {
  u32 r;
  asm("v_cvt_pk_bf16_f32 %0, %1, %2" : "=v"(r) : "v"(lo), "v"(hi));
  return r;
}

// ---------------------------------------------------------------------------
// fp32 -> bf16 elementwise convert for q/k/v activations. 8 elems/thread.
__global__ __launch_bounds__(256) void convert_k(const float* __restrict__ s0,
                                                 const float* __restrict__ s1,
                                                 const float* __restrict__ s2,
                                                 bf16* __restrict__ d0,
                                                 bf16* __restrict__ d1,
                                                 bf16* __restrict__ d2) {
  const float* s = (blockIdx.z == 0) ? s0 : (blockIdx.z == 1) ? s1 : s2;
  bf16* d = (blockIdx.z == 0) ? d0 : (blockIdx.z == 1) ? d1 : d2;
  const size_t i = ((size_t)blockIdx.x * 256 + threadIdx.x) * 8;
  f32x4 a = *(const f32x4*)(s + i);
  f32x4 b = *(const f32x4*)(s + i + 4);
  bf16x8 o;
#pragma unroll
  for (int j = 0; j < 4; j++) { o[j] = (bf16)a[j]; o[j + 4] = (bf16)b[j]; }
  *(bf16x8*)(d + i) = o;
}

// ---------------------------------------------------------------------------
// Transpose 4 fp32 1024x1024 weights -> bf16 W^T[n][k] in ws.
__global__ __launch_bounds__(256) void transposeW_k(
    const float* __restrict__ w0, const float* __restrict__ w1,
    const float* __restrict__ w2, const float* __restrict__ w3,
    bf16* __restrict__ t0, bf16* __restrict__ t1,
    bf16* __restrict__ t2, bf16* __restrict__ t3) {
  const float* src = (blockIdx.z == 0) ? w0 : (blockIdx.z == 1) ? w1
                     : (blockIdx.z == 2) ? w2 : w3;
  bf16* dst = (blockIdx.z == 0) ? t0 : (blockIdx.z == 1) ? t1
              : (blockIdx.z == 2) ? t2 : t3;
  __shared__ float tile[32][33];
  const int tx = threadIdx.x, ty = threadIdx.y;  // 32 x 8
  const int x0 = blockIdx.x * 32, y0 = blockIdx.y * 32;
#pragma unroll
  for (int r = 0; r < 4; r++)
    tile[ty + r * 8][tx] = src[(size_t)(y0 + ty + r * 8) * DM + x0 + tx];
  __syncthreads();
#pragma unroll
  for (int r = 0; r < 4; r++)
    dst[(size_t)(x0 + ty + r * 8) * DM + y0 + tx] = (bf16)tile[tx][ty + r * 8];
}

// ---------------------------------------------------------------------------
struct GArgs { const void* A; const bf16* Bt; const float* bias; void* C; };
struct GArgs3 { GArgs g[3]; };

// ---------------------------------------------------------------------------
// 256x256 tile, BK=64, 512 threads = 8 waves (2M x 4N), per-wave 128x64.
// Phase template (T3): 4 phases/K-tile, each = ds-subtile + 16 MFMA + barrier.
// T2: chunk-XOR swizzle (chunk ^= row&7) -> conflict-free ds_read_b128;
// applied as inverse-swizzled GLOBAL source + swizzled ds_read (rule #21).
// Full next-tile prefetch at phase 0, one vmcnt(0)+barrier per K-tile.
// T5: setprio(1) around MFMA clusters. T1: XCD-chunked work mapping.
__global__ __launch_bounds__(512, 2) void gemm256_k(GArgs3 args, int M, int N,
                                                    int K, int tilesY, int tilesX) {
  // T1 bijective XCD chunk map (nwg % 8 == 0): XCD k gets contiguous work.
  const int nwg = gridDim.x;
  const int id = blockIdx.x;
  const int wgid = (id & 7) * (nwg >> 3) + (id >> 3);
  const int perz = tilesY * tilesX;
  const int z = wgid / perz;
  const int rem = wgid - z * perz;
  const int ty = rem / tilesX, tx = rem - (rem / tilesX) * tilesX;
  const GArgs ga = args.g[z];
  const int m0 = ty * 256, n0 = tx * 256;

  __shared__ __align__(16) bf16 As[2][16384];  // [buf][row*64 + col], swizzled
  __shared__ __align__(16) bf16 Bs[2][16384];

  const int tid = threadIdx.x;
  const int lane = tid & 63, w = tid >> 6;
  const int l15 = lane & 15, q = lane >> 4;
  const int wr = w >> 2, wc = w & 3;

  // ---- staging source pointers: LDS chunk c holds G[row][ (c&7) ^ (row&7) ]
  const bf16* gA[4];
  const bf16* gB[4];
#pragma unroll
  for (int i = 0; i < 4; i++) {
    const int ci = i * 512 + w * 64 + lane;
    const int row = ci >> 3, ch = ci & 7, sc = ch ^ (row & 7);
    gA[i] = (const bf16*)ga.A + (size_t)(m0 + row) * K + sc * 8;
    gB[i] = ga.Bt + (size_t)(n0 + row) * K + sc * 8;
  }

  // ---- swizzled read column offsets: chunk (kk*4+q) ^ (row&7), row&7==l15&7
  const int cA0 = ((q) ^ (l15 & 7)) * 8;
  const int cA1 = ((4 + q) ^ (l15 & 7)) * 8;

  f32x4 acc[8][4] = {};

  // ---- prologue: stage tile 0 -> buf 0
#pragma unroll
  for (int i = 0; i < 4; i++) {
    gload_lds16(gA[i], &As[0][(i * 512 + w * 64) * 8]);
    gload_lds16(gB[i], &Bs[0][(i * 512 + w * 64) * 8]);
  }
  asm volatile("s_waitcnt vmcnt(0)" ::: "memory");
  __builtin_amdgcn_s_barrier();

  const int NT = K >> 6;
  for (int t = 0; t < NT; ++t) {
    const int cur = t & 1;
    const bf16* Ac = As[cur];
    const bf16* Bc = Bs[cur];

    bf16x8 a[4][2], b[2][2][2];
    // ---- phase 0: quadrant (mh=0, nh=0); ds A(mh0)+B(nh0); issue full
    //      next-tile prefetch (8 gload_lds) -> lands within this tile.
#pragma unroll
    for (int mt = 0; mt < 4; mt++) {
      const int row = wr * 128 + mt * 16 + l15;
      a[mt][0] = *(const bf16x8*)(Ac + row * 64 + cA0);
      a[mt][1] = *(const bf16x8*)(Ac + row * 64 + cA1);
    }
#pragma unroll
    for (int nt = 0; nt < 2; nt++) {
      const int row = wc * 64 + nt * 16 + l15;
      b[0][nt][0] = *(const bf16x8*)(Bc + row * 64 + cA0);
      b[0][nt][1] = *(const bf16x8*)(Bc + row * 64 + cA1);
    }
    if (t + 1 < NT) {
      const int k0 = (t + 1) << 6;
      bf16* An = As[cur ^ 1];
      bf16* Bn = Bs[cur ^ 1];
#pragma unroll
      for (int i = 0; i < 4; i++) {
        gload_lds16(gA[i] + k0, An + (i * 512 + w * 64) * 8);
        gload_lds16(gB[i] + k0, Bn + (i * 512 + w * 64) * 8);
      }
    }
    __builtin_amdgcn_s_setprio(1);
#pragma unroll
    for (int mt = 0; mt < 4; mt++)
#pragma unroll
      for (int nt = 0; nt < 2; nt++)
#pragma unroll
        for (int kk = 0; kk < 2; kk++)
          acc[mt][nt] = __builtin_amdgcn_mfma_f32_16x16x32_bf16(
              a[mt][kk], b[0][nt][kk], acc[mt][nt], 0, 0, 0);
    __builtin_amdgcn_s_setprio(0);
    __builtin_amdgcn_s_barrier();

    // ---- phase 1: (mh=0, nh=1); load B(nh1), reuse A
#pragma unroll
    for (int nt = 0; nt < 2; nt++) {
      const int row = wc * 64 + 32 + nt * 16 + l15;
      b[1][nt][0] = *(const bf16x8*)(Bc + row * 64 + cA0);
      b[1][nt][1] = *(const bf16x8*)(Bc + row * 64 + cA1);
    }
    __builtin_amdgcn_s_setprio(1);
#pragma unroll
    for (int mt = 0; mt < 4; mt++)
#pragma unroll
      for (int nt = 0; nt < 2; nt++)
#pragma unroll
        for (int kk = 0; kk < 2; kk++)
          acc[mt][2 + nt] = __builtin_amdgcn_mfma_f32_16x16x32_bf16(
              a[mt][kk], b[1][nt][kk], acc[mt][2 + nt], 0, 0, 0);
    __builtin_amdgcn_s_setprio(0);
    __builtin_amdgcn_s_barrier();

    // ---- phase 2: (mh=1, nh=1); load A(mh1), reuse B(nh1)
#pragma unroll
    for (int mt = 0; mt < 4; mt++) {
      const int row = wr * 128 + 64 + mt * 16 + l15;
      a[mt][0] = *(const bf16x8*)(Ac + row * 64 + cA0);
      a[mt][1] = *(const bf16x8*)(Ac + row * 64 + cA1);
    }
    __builtin_amdgcn_s_setprio(1);
#pragma unroll
    for (int mt = 0; mt < 4; mt++)
#pragma unroll
      for (int nt = 0; nt < 2; nt++)
#pragma unroll
        for (int kk = 0; kk < 2; kk++)
          acc[4 + mt][2 + nt] = __builtin_amdgcn_mfma_f32_16x16x32_bf16(
              a[mt][kk], b[1][nt][kk], acc[4 + mt][2 + nt], 0, 0, 0);
    __builtin_amdgcn_s_setprio(0);
    __builtin_amdgcn_s_barrier();

    // ---- phase 3: (mh=1, nh=0); all-register reuse
    __builtin_amdgcn_s_setprio(1);
#pragma unroll
    for (int mt = 0; mt < 4; mt++)
#pragma unroll
      for (int nt = 0; nt < 2; nt++)
#pragma unroll
        for (int kk = 0; kk < 2; kk++)
          acc[4 + mt][nt] = __builtin_amdgcn_mfma_f32_16x16x32_bf16(
              a[mt][kk], b[0][nt][kk], acc[4 + mt][nt], 0, 0, 0);
    __builtin_amdgcn_s_setprio(0);
    // ---- tile end: next tile must be landed (all waves), buffers swap
    asm volatile("s_waitcnt vmcnt(0)" ::: "memory");
    __builtin_amdgcn_s_barrier();
  }

  // ---- epilogue: C/D layout col=lane&15, row=(lane>>4)*4+reg
#pragma unroll
  for (int nh = 0; nh < 2; nh++)
#pragma unroll
    for (int nt = 0; nt < 2; nt++) {
      const int col = n0 + wc * 64 + nh * 32 + nt * 16 + l15;
      const float bv = ga.bias[col];
#pragma unroll
      for (int mh = 0; mh < 2; mh++)
#pragma unroll
        for (int mt = 0; mt < 4; mt++) {
          const int row = m0 + wr * 128 + mh * 64 + mt * 16 + q * 4;
          f32x4 v = acc[mh * 4 + mt][nh * 2 + nt];
#pragma unroll
          for (int r = 0; r < 4; r++)
            ((bf16*)ga.C)[(size_t)(row + r) * N + col] = (bf16)(v[r] + bv);
        }
    }
}

// ---------------------------------------------------------------------------
// 128x128 tile, BK=32 GEMM (m97 structure). Used for out-proj (CF32) and the
// slow-path fp32-A QKV. CF32 path gets a T1 XCD-chunked remap (grid 8x32).
template <bool AF32, bool CF32>
__global__ __launch_bounds__(256) void gemm_k(GArgs3 args, int M, int N, int K) {
  const GArgs ga = args.g[blockIdx.z];
  __shared__ __align__(16) bf16 As[128 * 32];  // [m][k], stride 32
  __shared__ __align__(16) bf16 Bs[128 * 32];  // [n][k], stride 32
  const int tid = threadIdx.x;
  const int lane = tid & 63, w = tid >> 6;
  const int l15 = lane & 15, q = lane >> 4;
  const int wr = w >> 1, wc = w & 1;

  int bx = blockIdx.x, by = blockIdx.y;
  if constexpr (CF32) {  // T1: same-XCD blocks share A-panels (y) + weight
    const int nb = gridDim.x * gridDim.y;
    const int id = by * gridDim.x + bx;
    const int wg = (id & 7) * (nb >> 3) + (id >> 3);
    bx = wg % gridDim.x;
    by = wg / gridDim.x;
  }
  const int m0 = by * 128, n0 = bx * 128;

  const int c0 = w * 128 + lane;       // wave-contiguous for global_load_lds
  const int c1 = c0 + 64;
  const int r0 = c0 >> 2, r1 = c1 >> 2, koff = (c0 & 3) * 8;
  const bf16* gB0 = ga.Bt + (size_t)(n0 + r0) * K + koff;
  const bf16* gB1 = ga.Bt + (size_t)(n0 + r1) * K + koff;
  bf16* lA0 = As + (w * 2 + 0) * 512;  // 64 lanes x 16B = 512 elems
  bf16* lA1 = As + (w * 2 + 1) * 512;
  bf16* lB0 = Bs + (w * 2 + 0) * 512;
  bf16* lB1 = Bs + (w * 2 + 1) * 512;

  const float* pA0 = nullptr;
  const float* pA1 = nullptr;
  f32x4 t00, t01, t10, t11;
  if constexpr (AF32) {
    const float* A = (const float*)ga.A;
    pA0 = A + (size_t)(m0 + r0) * K + koff;
    pA1 = A + (size_t)(m0 + r1) * K + koff;
    t00 = *(const f32x4*)pA0; t01 = *(const f32x4*)(pA0 + 4);
    t10 = *(const f32x4*)pA1; t11 = *(const f32x4*)(pA1 + 4);
  }

  f32x4 acc[4][4] = {};

  for (int k0 = 0; k0 < K; k0 += 32) {
    if constexpr (AF32) {
      bf16x8 va0, va1;
#pragma unroll
      for (int j = 0; j < 4; j++) {
        va0[j] = (bf16)t00[j]; va0[j + 4] = (bf16)t01[j];
        va1[j] = (bf16)t10[j]; va1[j + 4] = (bf16)t11[j];
      }
      *(bf16x8*)(lA0 + lane * 8) = va0;
      *(bf16x8*)(lA1 + lane * 8) = va1;
    } else {
      const bf16* A = (const bf16*)ga.A;
      gload_lds16(A + (size_t)(m0 + r0) * K + koff + k0, lA0);
      gload_lds16(A + (size_t)(m0 + r1) * K + koff + k0, lA1);
    }
    gload_lds16(gB0 + k0, lB0);
    gload_lds16(gB1 + k0, lB1);
    __syncthreads();  // drains async copies + LDS writes

    bf16x8 a[4], b[4];
#pragma unroll
    for (int mt = 0; mt < 4; mt++)
      a[mt] = *(const bf16x8*)(As + (wr * 64 + mt * 16 + l15) * 32 + q * 8);
#pragma unroll
    for (int nt = 0; nt < 4; nt++)
      b[nt] = *(const bf16x8*)(Bs + (wc * 64 + nt * 16 + l15) * 32 + q * 8);

    if constexpr (AF32) {  // prefetch next A chunk; overlaps MFMA below
      const int kn = (k0 + 32 < K) ? k0 + 32 : k0;
      t00 = *(const f32x4*)(pA0 + kn); t01 = *(const f32x4*)(pA0 + kn + 4);
      t10 = *(const f32x4*)(pA1 + kn); t11 = *(const f32x4*)(pA1 + kn + 4);
    }

#pragma unroll
    for (int mt = 0; mt < 4; mt++)
#pragma unroll
      for (int nt = 0; nt < 4; nt++)
        acc[mt][nt] = __builtin_amdgcn_mfma_f32_16x16x32_bf16(a[mt], b[nt],
                                                              acc[mt][nt], 0, 0, 0);
    __syncthreads();
  }

  // C/D layout: col = lane&15, row = (lane>>4)*4 + reg.
#pragma unroll
  for (int nt = 0; nt < 4; nt++) {
    const int col = n0 + wc * 64 + nt * 16 + l15;
    const float bv = ga.bias[col];
#pragma unroll
    for (int mt = 0; mt < 4; mt++) {
      const int row = m0 + wr * 64 + mt * 16 + q * 4;
#pragma unroll
      for (int r = 0; r < 4; r++) {
        const float val = acc[mt][nt][r] + bv;
        if constexpr (CF32)
          ((float*)ga.C)[(size_t)(row + r) * N + col] = val;
        else
          ((bf16*)ga.C)[(size_t)(row + r) * N + col] = (bf16)val;
      }
    }
  }
}

// ---------------------------------------------------------------------------
// Causal flash attention, no-max softmax. 32x32x16 MFMA, swapped QK^T
// (S^T = K@Q^T) so P stays in registers (cvt_pk_bf16 + permlane32_swap).
// 4 waves = (q-half qh) x (key-half kh). Each wave accumulates a partial
// O^T[64d][32q] over its key-half; one LDS reduction at block end.
__global__ __launch_bounds__(256, 4) void attn_k(const bf16* __restrict__ Qp,
                                                 const bf16* __restrict__ Kp,
                                                 const bf16* __restrict__ Vp,
                                                 bf16* __restrict__ Op) {
  const int g = blockIdx.x;          // 0..1023
  const int c = g & 255, sl = g >> 8;
  const int u = c & 31;
  const int xt = (sl == 0) ? u : (sl == 1) ? 31 - u
                 : (sl == 2) ? (u ^ 16) : 31 - (u ^ 16);
  const int h = (c >> 5) | ((sl & 1) << 3);
  const int b = sl >> 1;
  const int i0 = xt * 64;

  const int tid = threadIdx.x;
  const int lane = tid & 63, w = tid >> 6;
  const int l31 = lane & 31, hi = lane >> 5;
  const int qh = w >> 1, kh = w & 1;

  __shared__ __align__(16) char smem[36864];
  bf16 (*Ks)[64][72] = (bf16 (*)[64][72])smem;             // [2][64][72]
  bf16 (*Vts)[64][72] = (bf16 (*)[64][72])(smem + 18432);  // [2][64][72] ([d][k])

  const size_t headoff = (size_t)b * S_ * DM + h * HD;
  const bf16* Kb = Kp + headoff;
  const bf16* Vb = Vp + headoff;

  const int kr0 = tid >> 3, kr1 = 32 + (tid >> 3), kcb = (tid & 7) * 8;
  const int d0 = (tid & 31) * 2, kq = (tid >> 5) * 8;
  const float QSCALE = 0.04508422f;  // log2(e)/32

  // ---- Q -> registers in B-frag layout (n=q=l31, k=kk*16+hi*8+j), prescaled
  bf16x8 qreg[4];
  {
    const bf16* qb = Qp + headoff + (size_t)(i0 + qh * 32 + l31) * DM + hi * 8;
#pragma unroll
    for (int kk = 0; kk < 4; kk++) {
      bf16x8 v = *(const bf16x8*)(qb + kk * 16);
      bf16x8 o;
#pragma unroll
      for (int j = 0; j < 8; j++) o[j] = (bf16)((float)v[j] * QSCALE);
      qreg[kk] = o;
    }
  }

  // ---- stage K/V tile j0=0 into buf 0
  {
    bf16x8 k0v = *(const bf16x8*)(Kb + (size_t)kr0 * DM + kcb);
    bf16x8 k1v = *(const bf16x8*)(Kb + (size_t)kr1 * DM + kcb);
    *(bf16x8*)&Ks[0][kr0][kcb] = k0v;
    *(bf16x8*)&Ks[0][kr1][kcb] = k1v;
    bf16x8 vlo, vhi;
#pragma unroll
    for (int j = 0; j < 8; j++) {
      bf16x2 p = *(const bf16x2*)(Vb + (size_t)(kq + j) * DM + d0);
      vlo[j] = p[0]; vhi[j] = p[1];
    }
    *(bf16x8*)&Vts[0][d0][kq] = vlo;
    *(bf16x8*)&Vts[0][d0 + 1][kq] = vhi;
  }
  __syncthreads();

  f32x16 oacc0 = {}, oacc1 = {};  // O^T partial: d-tiles 0..31 / 32..63, col q
  float rsum = 0.f;
  int buf = 0;

  for (int j0 = 0; j0 <= i0; j0 += 64, buf ^= 1) {
    // ---- prefetch next K/V tile into regs (T14: issue early, write late)
    const int jn = (j0 + 64 <= i0) ? j0 + 64 : 0;
    bf16x8 kpre0 = *(const bf16x8*)(Kb + (size_t)(jn + kr0) * DM + kcb);
    bf16x8 kpre1 = *(const bf16x8*)(Kb + (size_t)(jn + kr1) * DM + kcb);
    bf16x2 vpre[8];
#pragma unroll
    for (int j = 0; j < 8; j++)
      vpre[j] = *(const bf16x2*)(Vb + (size_t)(jn + kq + j) * DM + d0);

    const bool diag = (j0 == i0);
    if (!(diag && kh > qh)) {  // (qh=0,kh=1) diagonal tile is fully masked
      // ---- S^T = K @ Q^T : A = K[key=kh*32+l31][hd], B = Q regs
      f32x16 sacc = {};
      __builtin_amdgcn_s_setprio(1);
#pragma unroll
      for (int kk = 0; kk < 4; kk++) {
        bf16x8 ka = *(const bf16x8*)&Ks[buf][kh * 32 + l31][kk * 16 + hi * 8];
        sacc = __builtin_amdgcn_mfma_f32_32x32x16_bf16(ka, qreg[kk], sacc, 0, 0, 0);
      }
      __builtin_amdgcn_s_setprio(0);

      // ---- p = exp2(s). C-layout: col=q=l31, row=key=(r&3)+8*(r>>2)+4*hi
      float p[16];
      if (diag) {
        const int qrl = qh * 32 + l31;
#pragma unroll
        for (int r = 0; r < 16; r++) {
          const int keyl = kh * 32 + (r & 3) + 8 * (r >> 2) + 4 * hi;
          p[r] = (keyl <= qrl) ? __builtin_amdgcn_exp2f(sacc[r]) : 0.f;
          rsum += p[r];
        }
      } else {
#pragma unroll
        for (int r = 0; r < 16; r++) {
          p[r] = __builtin_amdgcn_exp2f(sacc[r]);
          rsum += p[r];
        }
      }

      // ---- pack quads to bf16 words
      u32 Aq[4][2];
#pragma unroll
      for (int t = 0; t < 4; t++) {
        Aq[t][0] = cvt_pk_bf16(p[4 * t + 0], p[4 * t + 1]);
        Aq[t][1] = cvt_pk_bf16(p[4 * t + 2], p[4 * t + 3]);
      }
      // ---- exchange to PV B-frag via permlane32_swap
      bf16x8 pb[2];
#pragma unroll
      for (int s = 0; s < 2; s++) {
        auto e0 = __builtin_amdgcn_permlane32_swap(Aq[2 * s][0], Aq[2 * s + 1][0], false, false);
        auto e1 = __builtin_amdgcn_permlane32_swap(Aq[2 * s][1], Aq[2 * s + 1][1], false, false);
        union { u32 u[4]; bf16x8 v; } cv;
        cv.u[0] = e0[0]; cv.u[1] = e1[0]; cv.u[2] = e0[1]; cv.u[3] = e1[1];
        pb[s] = cv.v;
      }

      // ---- O^T += V^T @ P : A = Vts[d][key], B = pb (keys of this kh-half)
      __builtin_amdgcn_s_setprio(1);
#pragma unroll
      for (int s = 0; s < 2; s++) {
        bf16x8 va0 = *(const bf16x8*)&Vts[buf][l31][kh * 32 + s * 16 + hi * 8];
        bf16x8 va1 = *(const bf16x8*)&Vts[buf][32 + l31][kh * 32 + s * 16 + hi * 8];
        oacc0 = __builtin_amdgcn_mfma_f32_32x32x16_bf16(va0, pb[s], oacc0, 0, 0, 0);
        oacc1 = __builtin_amdgcn_mfma_f32_32x32x16_bf16(va1, pb[s], oacc1, 0, 0, 0);
      }
      __builtin_amdgcn_s_setprio(0);
    }

    // ---- write prefetched tile into the other buffer
    *(bf16x8*)&Ks[buf ^ 1][kr0][kcb] = kpre0;
    *(bf16x8*)&Ks[buf ^ 1][kr1][kcb] = kpre1;
    {
      bf16x8 vlo, vhi;
#pragma unroll
      for (int j = 0; j < 8; j++) { vlo[j] = vpre[j][0]; vhi[j] = vpre[j][1]; }
      *(bf16x8*)&Vts[buf ^ 1][d0][kq] = vlo;
      *(bf16x8*)&Vts[buf ^ 1][d0 + 1][kq] = vhi;
    }
    __syncthreads();  // single barrier: buf^1 writes visible, buf reads done
  }

  // ---- cross-wave (kh) reduction + transposed coalesced output ----
  float rtot_w = rsum + __shfl_xor(rsum, 32);
  float* osum = (float*)smem;             // [w][slot=8][lane=64][4] f32
  float* auxf = (float*)(smem + 32768);   // [w][32] rsum partials
#pragma unroll
  for (int m = 0; m < 2; m++) {
#pragma unroll
    for (int rq = 0; rq < 4; rq++) {
      f32x4 v4;
#pragma unroll
      for (int e = 0; e < 4; e++)
        v4[e] = m ? oacc1[rq * 4 + e] : oacc0[rq * 4 + e];
      *(f32x4*)(osum + w * 2048 + (m * 4 + rq) * 256 + lane * 4) = v4;
    }
  }
  if (lane < 32) auxf[w * 32 + lane] = rtot_w;
  __syncthreads();

  {
    const int q = tid >> 2, q31b = q & 31, qh2 = q >> 5;
    const float rtot = auxf[(qh2 * 2 + 0) * 32 + q31b] + auxf[(qh2 * 2 + 1) * 32 + q31b];
    const float rinv = 1.0f / rtot;
    const int dbase = (tid & 3) * 16;
    bf16* orow = Op + headoff + (size_t)(i0 + q) * DM + dbase;
#pragma unroll
    for (int gg = 0; gg < 2; gg++) {
      bf16x8 o8;
#pragma unroll
      for (int e = 0; e < 8; e++) {
        const int d = dbase + gg * 8 + e;
        const int base = (((d >> 5) << 2) | ((d >> 3) & 3)) * 256 +
                         (q31b + 32 * ((d >> 2) & 1)) * 4 + (d & 3);
        const float v = osum[(qh2 * 2 + 0) * 2048 + base] +
                        osum[(qh2 * 2 + 1) * 2048 + base];
        o8[e] = (bf16)(v * rinv);
      }
      *(bf16x8*)(orow + gg * 8) = o8;
    }
  }
}

// ---------------------------------------------------------------------------
extern "C" void kernel_launch(void* const* d_in, const int* in_sizes, int n_in,
                              void* d_out, int out_size, void* d_ws, size_t ws_size,
                              hipStream_t stream) {
  const float* q_in = (const float*)d_in[0];
  const float* k_in = (const float*)d_in[1];
  const float* v_in = (const float*)d_in[2];
  // d_in[3] = causal mask, implemented analytically
  const float* Wq = (const float*)d_in[4];
  const float* bq = (const float*)d_in[5];
  const float* Wk = (const float*)d_in[6];
  const float* bk = (const float*)d_in[7];
  const float* Wv = (const float*)d_in[8];
  const float* bv = (const float*)d_in[9];
  const float* Wo = (const float*)d_in[10];
  const float* bo = (const float*)d_in[11];

  bf16* ws = (bf16*)d_ws;
  const size_t NQ = (size_t)B_ * S_ * DM;  // 4M elements
  bf16* Qp = ws;                           // attn writes in-place
  bf16* Kp = ws + NQ;
  bf16* Vp = ws + 2 * NQ;
  bf16* WqT = ws + 3 * NQ;                 // bf16 W^T, 1M elems each
  bf16* WkT = WqT + (size_t)DM * DM;
  bf16* WvT = WkT + (size_t)DM * DM;
  bf16* WoT = WvT + (size_t)DM * DM;       // 32 MB so far
  bf16* qb = WoT + (size_t)DM * DM;        // converted activations (fast path)
  bf16* kb = qb + NQ;
  bf16* vb = kb + NQ;                      // 56 MB total (fast path)

  const bool fast = ws_size >= (size_t)(28 * 1024 * 1024) * 2;  // 56 MB

  transposeW_k<<<dim3(32, 32, 4), dim3(32, 8), 0, stream>>>(
      Wq, Wk, Wv, Wo, WqT, WkT, WvT, WoT);

  if (fast) {
    convert_k<<<dim3((B_ * S_ * DM) / (256 * 8), 1, 3), 256, 0, stream>>>(
        q_in, k_in, v_in, qb, kb, vb);
    GArgs3 g3;
    g3.g[0] = {qb, WqT, bq, Qp};
    g3.g[1] = {kb, WkT, bk, Kp};
    g3.g[2] = {vb, WvT, bv, Vp};
    // 256^2 8-wave phase kernel: 16x4 tiles x 3 matrices = 192 blocks
    gemm256_k<<<dim3(192), 512, 0, stream>>>(g3, B_ * S_, DM, DM, 16, 4);
  } else {
    GArgs3 g3;
    g3.g[0] = {q_in, WqT, bq, Qp};
    g3.g[1] = {k_in, WkT, bk, Kp};
    g3.g[2] = {v_in, WvT, bv, Vp};
    gemm_k<true, false><<<dim3(DM / 128, (B_ * S_) / 128, 3), 256, 0, stream>>>(
        g3, B_ * S_, DM, DM);
  }

  attn_k<<<dim3(1024, 1, 1), 256, 0, stream>>>(Qp, Kp, Vp, Qp);

  GArgs3 gp;
  gp.g[0] = {Qp, WoT, bo, d_out};
  gp.g[1] = gp.g[0];
  gp.g[2] = gp.g[0];
  gemm_k<false, true><<<dim3(DM / 128, (B_ * S_) / 128, 1), 256, 0, stream>>>(
      gp, B_ * S_, DM, DM);
}